// Round 3
// baseline (21.134 us; speedup 1.0000x reference)
//
#include <hip/hip_runtime.h>

// Sizes fixed by the reference: B=512, H=1024, D=5, 32 multivector comps.
#define NB 512
#define NH 1024
#define ND 5
#define NCH 8               // h-chunks
#define CH (NH / NCH)       // 128 h per chunk
// 1 - (1-dt)^N_FREE = 1 - 0.9^10
#define SCALE 0.6513215599f

// Cayley sign for Cl(4,1), metric diag(1,1,1,1,-1): e_a*e_b = sign(a,b)*e_{a^b}
__device__ __forceinline__ float cl_sign(int a, int b) {
    int cnt = 0;
    int aa = a >> 1;
    while (aa) { cnt += __popc(aa & b); aa >>= 1; }
    float s = (cnt & 1) ? -1.0f : 1.0f;
    if ((a & b) & 16) s = -s;   // e5*e5 = -1 (bit 4)
    return s;
}

// Kernel 1: per (d,hc) block -> partial G over its h-chunk (registers),
// then sign-transform the partial G into a partial K (transform is linear
// in G so it commutes with the h-reduction).
// Kp[hc*5120 + d*1024 + r*32 + k]; grid = ND*NCH = 40, block = 256.
__global__ void k_partK(const float* __restrict__ Win, const float* __restrict__ Wout,
                        float* __restrict__ Kp) {
    const int d  = blockIdx.x >> 3;
    const int hc = blockIdx.x & 7;
    const int h0 = hc * CH;
    __shared__ __align__(16) float as[CH][32];
    __shared__ __align__(16) float bs[CH][32];
    __shared__ float gs[1024];
    __shared__ float sg[1024];
    const int t = threadIdx.x;
    // float4-staged loads of this chunk's Win[:,d,:] and Wout rows
    {
        const int row = t >> 3;            // 0..31
        const int c4  = (t & 7) * 4;       // 0,4,...,28
        #pragma unroll
        for (int j = 0; j < 4; ++j) {
            const int h = h0 + row + j * 32;
            *(float4*)&as[row + j * 32][c4] = *(const float4*)&Win[h * (ND * 32) + d * 32 + c4];
            *(float4*)&bs[row + j * 32][c4] = *(const float4*)&Wout[h * 32 + c4];
        }
    }
    for (int i = t; i < 1024; i += 256) sg[i] = cl_sign(i >> 5, i & 31);
    __syncthreads();
    // 2x2 register tile over (s,q), K=CH reduction
    const int s0 = (t >> 4) << 1;
    const int q0 = (t & 15) << 1;
    float a00 = 0.f, a01 = 0.f, a10 = 0.f, a11 = 0.f;
    #pragma unroll
    for (int h = 0; h < CH; ++h) {
        const float2 av = *(const float2*)&as[h][s0];
        const float2 bv = *(const float2*)&bs[h][q0];
        a00 += av.x * bv.x; a01 += av.x * bv.y;
        a10 += av.y * bv.x; a11 += av.y * bv.y;
    }
    gs[s0 * 32 + q0]           = a00;
    gs[s0 * 32 + q0 + 1]       = a01;
    gs[(s0 + 1) * 32 + q0]     = a10;
    gs[(s0 + 1) * 32 + q0 + 1] = a11;
    __syncthreads();
    // sign-transform partial G -> partial K (4 outputs/thread)
    for (int i0 = 0; i0 < 1024; i0 += 256) {
        const int i = i0 + t;
        const int r = i >> 5, k = i & 31;
        float acc = 0.f;
        #pragma unroll
        for (int s = 0; s < 32; ++s) {
            const int p = r ^ s;
            const int q = p ^ k;
            acc += sg[r * 32 + s] * sg[p * 32 + q] * gs[s * 32 + q];
        }
        Kp[hc * (ND * 1024) + d * 1024 + i] = SCALE * acc;
    }
}

// Kernel 2: reduce the NCH partial-K slabs into LDS, then pred.
// grid = NB/8 = 64, block = 256 (= 8 b x 32 k).
__global__ void k_pred(const float* __restrict__ x, const float* __restrict__ Kp,
                       float* __restrict__ out) {
    __shared__ __align__(16) float ks[ND * 1024];
    __shared__ __align__(16) float xs[8 * ND * 32];
    const int t = threadIdx.x;
    const int b0 = blockIdx.x * 8;
    // partial-K reduction, float4 coalesced (5 iters/thread)
    for (int i = t; i < ND * 1024 / 4; i += 256) {
        float4 sum = ((const float4*)Kp)[i];
        #pragma unroll
        for (int hc = 1; hc < NCH; ++hc) {
            const float4 v = ((const float4*)Kp)[hc * (ND * 1024 / 4) + i];
            sum.x += v.x; sum.y += v.y; sum.z += v.z; sum.w += v.w;
        }
        ((float4*)ks)[i] = sum;
    }
    for (int i = t; i < 8 * ND * 32 / 4; i += 256)
        ((float4*)xs)[i] = ((const float4*)&x[b0 * (ND * 32)])[i];
    __syncthreads();
    const int bl = t >> 5, k = t & 31;
    float acc = 0.f;
    #pragma unroll
    for (int d = 0; d < ND; ++d) {
        #pragma unroll
        for (int r4 = 0; r4 < 8; ++r4) {
            const float4 xv = *(const float4*)&xs[bl * 160 + d * 32 + r4 * 4];
            acc += xv.x * ks[d * 1024 + (r4 * 4 + 0) * 32 + k];
            acc += xv.y * ks[d * 1024 + (r4 * 4 + 1) * 32 + k];
            acc += xv.z * ks[d * 1024 + (r4 * 4 + 2) * 32 + k];
            acc += xv.w * ks[d * 1024 + (r4 * 4 + 3) * 32 + k];
        }
    }
    out[(b0 + bl) * 32 + k] = acc;
}

extern "C" void kernel_launch(void* const* d_in, const int* in_sizes, int n_in,
                              void* d_out, int out_size, void* d_ws, size_t ws_size,
                              hipStream_t stream) {
    const float* x_mv  = (const float*)d_in[0];   // (512, 5, 32)
    const float* W_in  = (const float*)d_in[1];   // (1024, 5, 32)
    const float* W_out = (const float*)d_in[2];   // (1, 1024, 32)
    float* out = (float*)d_out;                   // (512, 1, 32)

    float* Kp = (float*)d_ws;                     // NCH * ND*1024 floats (160 KB)

    k_partK<<<ND * NCH, 256, 0, stream>>>(W_in, W_out, Kp);
    k_pred<<<NB / 8, 256, 0, stream>>>(x_mv, Kp, out);
}

// Round 4
// 15.963 us; speedup vs baseline: 1.3240x; 1.3240x over previous
//
#include <hip/hip_runtime.h>

// Sizes fixed by the reference: B=512, H=1024, D=5, 32 multivector comps.
#define NB 512
#define NH 1024
#define ND 5
#define NCH 32              // h-chunks for T partials
#define CH (NH / NCH)       // 32 h per chunk
// 1 - (1-dt)^N_FREE = 1 - 0.9^10
#define SCALE 0.6513215599f

// Cayley sign for Cl(4,1), metric diag(1,1,1,1,-1): e_a*e_b = sign(a,b)*e_{a^b}
__device__ __forceinline__ float cl_sign(int a, int b) {
    int cnt = 0;
    int aa = a >> 1;
    while (aa) { cnt += __popc(aa & b); aa >>= 1; }
    float s = (cnt & 1) ? -1.0f : 1.0f;
    if ((a & b) & 16) s = -s;   // e5*e5 = -1 (bit 4)
    return s;
}

// Kernel 1: per (d,hc) block -> partial G over its h-chunk, then collapse to
// partial T[d,m] = sum_s sign(s,s^m) * Gp[d,s,s^m]  (32 floats per block).
// Tp layout: [hc][d*32+m]. grid = ND*NCH = 160, block = 256.
__global__ void k_partT(const float* __restrict__ Win, const float* __restrict__ Wout,
                        float* __restrict__ Tp) {
    const int d  = blockIdx.x >> 5;        // 0..4
    const int hc = blockIdx.x & 31;        // 0..31
    const int h0 = hc * CH;
    __shared__ __align__(16) float as[CH][32];
    __shared__ __align__(16) float bs[CH][32];
    __shared__ float gs[1024];
    __shared__ float red[8][32];
    const int t = threadIdx.x;
    // float4-staged loads of this chunk's Win[:,d,:] and Wout rows
    {
        const int row = t >> 3;            // 0..31
        const int c4  = (t & 7) * 4;       // 0,4,...,28
        const int h = h0 + row;
        *(float4*)&as[row][c4] = *(const float4*)&Win[h * (ND * 32) + d * 32 + c4];
        *(float4*)&bs[row][c4] = *(const float4*)&Wout[h * 32 + c4];
    }
    __syncthreads();
    // 2x2 register tile over (s,q), reduction over CH h-values
    const int s0 = (t >> 4) << 1;
    const int q0 = (t & 15) << 1;
    float a00 = 0.f, a01 = 0.f, a10 = 0.f, a11 = 0.f;
    #pragma unroll
    for (int h = 0; h < CH; ++h) {
        const float2 av = *(const float2*)&as[h][s0];
        const float2 bv = *(const float2*)&bs[h][q0];
        a00 += av.x * bv.x; a01 += av.x * bv.y;
        a10 += av.y * bv.x; a11 += av.y * bv.y;
    }
    gs[s0 * 32 + q0]           = a00;
    gs[s0 * 32 + q0 + 1]       = a01;
    gs[(s0 + 1) * 32 + q0]     = a10;
    gs[(s0 + 1) * 32 + q0 + 1] = a11;
    __syncthreads();
    // collapse: partial T[m] = sum_s sign(s,s^m)*gs[s*32 + (s^m)]
    const int m = t & 31, grp = t >> 5;    // 8 s-groups of 4
    float acc = 0.f;
    #pragma unroll
    for (int j = 0; j < 4; ++j) {
        const int s = grp * 4 + j;
        acc += cl_sign(s, s ^ m) * gs[s * 32 + (s ^ m)];
    }
    red[grp][m] = acc;
    __syncthreads();
    if (t < 32) {
        float sum = 0.f;
        #pragma unroll
        for (int c = 0; c < 8; ++c) sum += red[c][t];
        Tp[hc * (ND * 32) + d * 32 + t] = sum;
    }
}

// Kernel 2: reduce T partials (160 floats), expand K[d,r,k] =
// SCALE*sign(r,r^k)*T[d,r^k] into LDS, then pred.
// grid = NB/8 = 64, block = 256 (= 8 b x 32 k).
__global__ void k_pred(const float* __restrict__ x, const float* __restrict__ Tp,
                       float* __restrict__ out) {
    __shared__ float Tl[ND * 32];
    __shared__ __align__(16) float ks[ND * 1024];
    __shared__ __align__(16) float xs[8 * ND * 32];
    const int t = threadIdx.x;
    const int b0 = blockIdx.x * 8;
    if (t < ND * 32) {
        float s = 0.f;
        #pragma unroll
        for (int hc = 0; hc < NCH; ++hc) s += Tp[hc * (ND * 32) + t];
        Tl[t] = s;
    }
    for (int i = t; i < 8 * ND * 32 / 4; i += 256)
        ((float4*)xs)[i] = ((const float4*)&x[b0 * (ND * 32)])[i];
    __syncthreads();
    // build Kl: 20 values per thread
    #pragma unroll
    for (int j = 0; j < ND * 1024 / 256; ++j) {
        const int i = j * 256 + t;
        const int d = i >> 10, r = (i >> 5) & 31, k = i & 31;
        ks[i] = SCALE * cl_sign(r, r ^ k) * Tl[d * 32 + (r ^ k)];
    }
    __syncthreads();
    const int bl = t >> 5, k = t & 31;
    float acc = 0.f;
    #pragma unroll
    for (int d = 0; d < ND; ++d) {
        #pragma unroll
        for (int r4 = 0; r4 < 8; ++r4) {
            const float4 xv = *(const float4*)&xs[bl * 160 + d * 32 + r4 * 4];
            acc += xv.x * ks[d * 1024 + (r4 * 4 + 0) * 32 + k];
            acc += xv.y * ks[d * 1024 + (r4 * 4 + 1) * 32 + k];
            acc += xv.z * ks[d * 1024 + (r4 * 4 + 2) * 32 + k];
            acc += xv.w * ks[d * 1024 + (r4 * 4 + 3) * 32 + k];
        }
    }
    out[(b0 + bl) * 32 + k] = acc;
}

extern "C" void kernel_launch(void* const* d_in, const int* in_sizes, int n_in,
                              void* d_out, int out_size, void* d_ws, size_t ws_size,
                              hipStream_t stream) {
    const float* x_mv  = (const float*)d_in[0];   // (512, 5, 32)
    const float* W_in  = (const float*)d_in[1];   // (1024, 5, 32)
    const float* W_out = (const float*)d_in[2];   // (1, 1024, 32)
    float* out = (float*)d_out;                   // (512, 1, 32)

    float* Tp = (float*)d_ws;                     // NCH * ND*32 floats (20 KB)

    k_partT<<<ND * NCH, 256, 0, stream>>>(W_in, W_out, Tp);
    k_pred<<<NB / 8, 256, 0, stream>>>(x_mv, Tp, out);
}